// Round 16
// baseline (238.683 us; speedup 1.0000x reference)
//
#include <hip/hip_runtime.h>
#include <hip/hip_bf16.h>

static constexpr int F1 = 256;   // input features
static constexpr int H1 = 64;    // hidden dim
static constexpr int C2 = 32;    // output classes
static constexpr int BSH2 = 8;   // bucket shift: 256 nodes per bucket
static constexpr int NBLK = 128; // persistent CSR blocks (== threads in prefix phase)

typedef __attribute__((ext_vector_type(8))) short short8;
typedef __attribute__((ext_vector_type(4))) float f32x4;
typedef __attribute__((ext_vector_type(4))) unsigned short ushort4v;

__device__ __forceinline__ unsigned short f2b(float f) {
  __hip_bfloat16 h = __float2bfloat16(f);
  unsigned short u;
  __builtin_memcpy(&u, &h, 2);
  return u;
}
__device__ __forceinline__ float b2f(unsigned short u) {
  return __uint_as_float(((unsigned)u) << 16);
}

// ---------------- edge-index access (robust to int32 or int64 storage) -----
__device__ __forceinline__ int ld_src(const int* __restrict__ ei, int E, int e, bool is64) {
  return is64 ? ei[2 * (size_t)e] : ei[e];
}
__device__ __forceinline__ int ld_dst(const int* __restrict__ ei, int E, int e, bool is64) {
  return is64 ? ei[2 * ((size_t)E + (size_t)e)] : ei[(size_t)E + (size_t)e];
}

// ---------------- grid-wide spin barrier (128 co-resident blocks) -----------
// bar[idx*2] = arrival counter, bar[idx*2+1] = release flag; both zeroed by
// hipMemsetAsync before every launch (replay-safe, poison-safe).
__device__ __forceinline__ void gsync(unsigned* bar, int idx, unsigned nblk) {
  __syncthreads();
  if (threadIdx.x == 0) {
    __threadfence();
    unsigned prev = atomicAdd(&bar[idx * 2], 1u);
    if (prev == nblk - 1u) {
      atomicExch(&bar[idx * 2 + 1], 1u);
    } else {
      while (atomicAdd(&bar[idx * 2 + 1], 0u) == 0u) {
        __builtin_amdgcn_s_sleep(2);
      }
    }
    __threadfence();
  }
  __syncthreads();
}

// ---------------- fused CSR build: wconv + hist + scans + partition + bin ---
__global__ __launch_bounds__(256) void k_csr(const int* __restrict__ ei, int E,
                                             const float* __restrict__ W1,
                                             const float* __restrict__ W2,
                                             unsigned short* __restrict__ wbt1,
                                             unsigned short* __restrict__ wbt2,
                                             unsigned* __restrict__ gcnt,
                                             unsigned* __restrict__ bcnt,
                                             unsigned* __restrict__ bo,
                                             unsigned* __restrict__ bar,
                                             unsigned* __restrict__ ebuf,
                                             unsigned* __restrict__ off,
                                             float* __restrict__ dis,
                                             int* __restrict__ srcbin,
                                             int nb, int n, int chunk) {
  __shared__ unsigned lhist[512];     // hist / partB bases
  __shared__ unsigned ldeg[256], loff[256], ts[256];
  __shared__ unsigned wsum_[4];
  __shared__ int s_is64;
  const int tid = threadIdx.x;
  const int blk = blockIdx.x;
  const int base = blk * chunk;
  const int bend = min(E, base + chunk);

  // ---- phase 0a: weight convert+transpose (one-time, split across blocks)
  {
    int gidx = blk * 256 + tid;
    if (gidx < 64 * 256) {
      int c = gidx >> 8, k = gidx & 255;
      wbt1[gidx] = f2b(W1[k * 64 + c]);
    }
    int g2 = gidx - 64 * 256;
    if (g2 >= 0 && g2 < 32 * 64) {
      int c = g2 >> 6, k = g2 & 63;
      wbt2[g2] = f2b(W2[k * 32 + c]);
    }
  }

  // ---- phase 0b: int64 detect (kept in register for later phases)
  if (tid == 0) s_is64 = 1;
  __syncthreads();
  {
    int nz = 0;
    for (int i = tid; i < 2048; i += 256) nz |= (ei[2 * i + 1] != 0);
    if (nz) s_is64 = 0;  // benign race
  }
  __syncthreads();
  const bool is64 = s_is64 != 0;

  // ---- phase 0c: per-(block,bucket) histogram + global bucket totals
  for (int i = tid; i < nb; i += 256) lhist[i] = 0;
  __syncthreads();
  for (int e = base + tid; e < bend; e += 256) {
    int d = ld_dst(ei, E, e, is64);
    atomicAdd(&lhist[d >> BSH2], 1u);
  }
  __syncthreads();
  for (int i = tid; i < nb; i += 256) {
    unsigned v = lhist[i];
    gcnt[(size_t)blk * nb + i] = v;
    if (v) atomicAdd(&bcnt[i], v);  // bcnt zeroed by memset
  }
  gsync(bar, 0, NBLK);

  // ---- phase 1: per-bucket exclusive prefix over blocks  (+ block 0: bo scan)
  {
    const int iters = (nb + NBLK - 1) / NBLK;
    for (int it = 0; it < iters; ++it) {
      int b = blk + it * NBLK;
      bool act = (tid < NBLK) && (b < nb);
      unsigned v = act ? gcnt[(size_t)tid * nb + b] : 0u;
      unsigned s = v;
#pragma unroll
      for (int o = 1; o < 64; o <<= 1) {
        unsigned u = __shfl_up(s, o, 64);
        if ((tid & 63) >= o) s += u;
      }
      if (tid == 63) wsum_[0] = s;
      __syncthreads();
      if (act && tid >= 64) s += wsum_[0];
      if (act) gcnt[(size_t)tid * nb + b] = s - v;  // block's base within bucket
      __syncthreads();
    }
    if (blk == 0) {  // exclusive scan of bucket totals -> bo (nb <= 512)
      unsigned l0 = (2 * tid + 0 < nb) ? bcnt[2 * tid + 0] : 0u;
      unsigned l1 = (2 * tid + 1 < nb) ? bcnt[2 * tid + 1] : 0u;
      ts[tid] = l0 + l1;
      __syncthreads();
      for (int o = 1; o < 256; o <<= 1) {
        unsigned v = ts[tid];
        unsigned add = (tid >= o) ? ts[tid - o] : 0u;
        __syncthreads();
        ts[tid] = v + add;
        __syncthreads();
      }
      unsigned prefix = (tid > 0) ? ts[tid - 1] : 0u;
      if (2 * tid + 0 < nb) bo[2 * tid + 0] = prefix;
      if (2 * tid + 1 < nb) bo[2 * tid + 1] = prefix + l0;
    }
  }
  gsync(bar, 1, NBLK);

  // ---- phase 2: partition pass B — packed (d_local<<24 | src) words
  for (int i = tid; i < nb; i += 256) lhist[i] = bo[i] + gcnt[(size_t)blk * nb + i];
  __syncthreads();
  for (int e = base + tid; e < bend; e += 256) {
    int s = ld_src(ei, E, e, is64);
    int d = ld_dst(ei, E, e, is64);
    unsigned pos = atomicAdd(&lhist[d >> BSH2], 1u);
    ebuf[pos] = ((unsigned)(d & 255) << 24) | (unsigned)s;
  }
  gsync(bar, 2, NBLK);

  // ---- phase 3: per-bucket CSR finish (deg, dis, off, binning)
  for (int b = blk; b < nb; b += NBLK) {
    const int node0 = b << BSH2;
    const int nn = min(256, n - node0);
    const unsigned beg = bo[b];
    const unsigned end = (b + 1 < nb) ? bo[b + 1] : (unsigned)E;
    ldeg[tid] = 0;
    __syncthreads();
    for (unsigned p = beg + tid; p < end; p += 256) {
      atomicAdd(&ldeg[ebuf[p] >> 24], 1u);
    }
    __syncthreads();
    unsigned v = ldeg[tid];
    unsigned s = v;
#pragma unroll
    for (int o = 1; o < 64; o <<= 1) {
      unsigned t = __shfl_up(s, o, 64);
      if ((tid & 63) >= o) s += t;
    }
    if ((tid & 63) == 63) wsum_[tid >> 6] = s;
    __syncthreads();
    unsigned add = 0;
    for (int w = 0; w < (tid >> 6); ++w) add += wsum_[w];
    s += add;
    loff[tid] = s - v;
    if (tid < nn) {
      off[node0 + tid] = beg + (s - v);
      dis[node0 + tid] = 1.0f / sqrtf((float)(v + 1u));  // + self-loop
    }
    ldeg[tid] = 0;  // reuse as fill counters
    __syncthreads();
    for (unsigned p = beg + tid; p < end; p += 256) {
      unsigned e = ebuf[p];
      unsigned li = e >> 24;
      unsigned pos = loff[li] + atomicAdd(&ldeg[li], 1u);
      srcbin[beg + pos] = (int)(e & 0xFFFFFFu);
    }
    __syncthreads();  // protect ldeg/loff reuse across loop iterations
  }
}

// ---------------- GEMM1 (MFMA): xw1' = dis .* (x @ W1), bf16 out -------------
// LDS staged by straight float4 COPY of pre-transposed wbt1 (no convert, no
// transpose, no bank conflicts). Padded [64][264] rows for conflict-free reads.
__global__ __launch_bounds__(256) void k_gemm1(const float* __restrict__ x,
                                               const unsigned short* __restrict__ wbt,
                                               const float* __restrict__ dis,
                                               unsigned short* __restrict__ y,
                                               int n) {
  __shared__ __align__(16) unsigned short wl[64][264];
  const int tid = threadIdx.x;
  for (int i = tid; i < 64 * 32; i += 256) {  // 2048 x 16B copies
    int row = i >> 5, c8 = (i & 31) * 8;
    *reinterpret_cast<float4*>(&wl[row][c8]) =
        *reinterpret_cast<const float4*>(wbt + (size_t)row * F1 + c8);
  }
  __syncthreads();

  const int wq = tid >> 6, l = tid & 63;
  const int lr = l & 15, lk = l >> 4;
  const int r0 = blockIdx.x * 128 + wq * 32;
  if (r0 >= n) return;  // n % 32 == 0 -> surviving waves are full

  f32x4 acc[2][4] = {};
  const float* xr0 = x + (size_t)(r0 + lr) * F1;
  const float* xr1 = xr0 + (size_t)16 * F1;
#pragma unroll
  for (int kc = 0; kc < 8; ++kc) {
    const int kb = kc * 32 + lk * 8;
    float4 p0 = *reinterpret_cast<const float4*>(xr0 + kb);
    float4 p1 = *reinterpret_cast<const float4*>(xr0 + kb + 4);
    float4 q0 = *reinterpret_cast<const float4*>(xr1 + kb);
    float4 q1 = *reinterpret_cast<const float4*>(xr1 + kb + 4);
    short8 a0, a1;
    a0[0] = f2b(p0.x); a0[1] = f2b(p0.y); a0[2] = f2b(p0.z); a0[3] = f2b(p0.w);
    a0[4] = f2b(p1.x); a0[5] = f2b(p1.y); a0[6] = f2b(p1.z); a0[7] = f2b(p1.w);
    a1[0] = f2b(q0.x); a1[1] = f2b(q0.y); a1[2] = f2b(q0.z); a1[3] = f2b(q0.w);
    a1[4] = f2b(q1.x); a1[5] = f2b(q1.y); a1[6] = f2b(q1.z); a1[7] = f2b(q1.w);
#pragma unroll
    for (int nt = 0; nt < 4; ++nt) {
      short8 bb = *reinterpret_cast<const short8*>(&wl[nt * 16 + lr][kb]);
      acc[0][nt] = __builtin_amdgcn_mfma_f32_16x16x32_bf16(a0, bb, acc[0][nt], 0, 0, 0);
      acc[1][nt] = __builtin_amdgcn_mfma_f32_16x16x32_bf16(a1, bb, acc[1][nt], 0, 0, 0);
    }
  }
  float dsc0[4], dsc1[4];
#pragma unroll
  for (int r = 0; r < 4; ++r) {
    dsc0[r] = dis[r0 + lk * 4 + r];
    dsc1[r] = dis[r0 + 16 + lk * 4 + r];
  }
  unsigned short* yb = y + (size_t)r0 * H1;
#pragma unroll
  for (int nt = 0; nt < 4; ++nt)
#pragma unroll
    for (int r = 0; r < 4; ++r) {
      yb[(size_t)(lk * 4 + r) * H1 + nt * 16 + lr] = f2b(acc[0][nt][r] * dsc0[r]);
      yb[(size_t)(16 + lk * 4 + r) * H1 + nt * 16 + lr] = f2b(acc[1][nt][r] * dsc1[r]);
    }
}

// ---------------- gather1: 4 streams x 16 lanes x ushort4 (round-6 shape) ----
__global__ __launch_bounds__(256) void k_gather1(const unsigned* __restrict__ off, int n, int E,
                                                 const int* __restrict__ srcbin,
                                                 const float* __restrict__ dis,
                                                 const unsigned short* __restrict__ xw,
                                                 const float* __restrict__ b1,
                                                 unsigned short* __restrict__ h) {
  const int w = blockIdx.x * 4 + (threadIdx.x >> 6);
  if (w >= n) return;
  const int lane = threadIdx.x & 63;
  const int c4 = (lane & 15) * 4;  // column group
  const int st = lane >> 4;        // edge stream 0..3
  const float dd = dis[w];
  const unsigned beg = off[w];
  const unsigned end = (w + 1 < n) ? off[w + 1] : (unsigned)E;

  float a0 = 0.f, a1 = 0.f, a2 = 0.f, a3 = 0.f;
  float e0 = 0.f, e1 = 0.f, e2 = 0.f, e3 = 0.f;
  if (st == 0) {  // self-loop (pre-scaled)
    ushort4v u = *reinterpret_cast<const ushort4v*>(xw + (size_t)w * H1 + c4);
    a0 = b2f(u[0]); a1 = b2f(u[1]); a2 = b2f(u[2]); a3 = b2f(u[3]);
  }
  unsigned p = beg + st;
  for (; p + 4 < end; p += 8) {  // x2 unroll per stream
    int s0 = srcbin[p];
    int s1 = srcbin[p + 4];
    ushort4v u0 = *reinterpret_cast<const ushort4v*>(xw + (size_t)s0 * H1 + c4);
    ushort4v u1 = *reinterpret_cast<const ushort4v*>(xw + (size_t)s1 * H1 + c4);
    a0 += b2f(u0[0]); a1 += b2f(u0[1]); a2 += b2f(u0[2]); a3 += b2f(u0[3]);
    e0 += b2f(u1[0]); e1 += b2f(u1[1]); e2 += b2f(u1[2]); e3 += b2f(u1[3]);
  }
  if (p < end) {
    int s0 = srcbin[p];
    ushort4v u0 = *reinterpret_cast<const ushort4v*>(xw + (size_t)s0 * H1 + c4);
    a0 += b2f(u0[0]); a1 += b2f(u0[1]); a2 += b2f(u0[2]); a3 += b2f(u0[3]);
  }
  a0 += e0; a1 += e1; a2 += e2; a3 += e3;
  a0 += __shfl_xor(a0, 16, 64); a1 += __shfl_xor(a1, 16, 64);
  a2 += __shfl_xor(a2, 16, 64); a3 += __shfl_xor(a3, 16, 64);
  a0 += __shfl_xor(a0, 32, 64); a1 += __shfl_xor(a1, 32, 64);
  a2 += __shfl_xor(a2, 32, 64); a3 += __shfl_xor(a3, 32, 64);
  if (st == 0) {
    float4 bb = *reinterpret_cast<const float4*>(b1 + c4);
    ushort4v hv;
    hv[0] = f2b(fmaxf(fmaf(a0, dd, bb.x), 0.0f));
    hv[1] = f2b(fmaxf(fmaf(a1, dd, bb.y), 0.0f));
    hv[2] = f2b(fmaxf(fmaf(a2, dd, bb.z), 0.0f));
    hv[3] = f2b(fmaxf(fmaf(a3, dd, bb.w), 0.0f));
    *reinterpret_cast<ushort4v*>(h + (size_t)w * H1 + c4) = hv;
  }
}

// ---------------- GEMM2 (MFMA, no LDS): xw2' = dis .* (h @ W2) ---------------
__global__ __launch_bounds__(256) void k_gemm2(const unsigned short* __restrict__ h,
                                               const unsigned short* __restrict__ wbt,
                                               const float* __restrict__ dis,
                                               unsigned short* __restrict__ y,
                                               int n) {
  const int tid = threadIdx.x;
  const int wq = tid >> 6, l = tid & 63;
  const int lr = l & 15, lk = l >> 4;
  const int r0 = blockIdx.x * 128 + wq * 32;
  if (r0 >= n) return;

  short8 bfrag[2][2];
#pragma unroll
  for (int kc = 0; kc < 2; ++kc)
#pragma unroll
    for (int nt = 0; nt < 2; ++nt)
      bfrag[kc][nt] =
          *reinterpret_cast<const short8*>(wbt + (size_t)(nt * 16 + lr) * H1 + kc * 32 + lk * 8);

  f32x4 acc[2][2] = {};
  const unsigned short* h0 = h + (size_t)(r0 + lr) * H1;
  const unsigned short* h1 = h0 + (size_t)16 * H1;
#pragma unroll
  for (int kc = 0; kc < 2; ++kc) {
    const int kb = kc * 32 + lk * 8;
    short8 a0 = *reinterpret_cast<const short8*>(h0 + kb);
    short8 a1 = *reinterpret_cast<const short8*>(h1 + kb);
#pragma unroll
    for (int nt = 0; nt < 2; ++nt) {
      acc[0][nt] = __builtin_amdgcn_mfma_f32_16x16x32_bf16(a0, bfrag[kc][nt], acc[0][nt], 0, 0, 0);
      acc[1][nt] = __builtin_amdgcn_mfma_f32_16x16x32_bf16(a1, bfrag[kc][nt], acc[1][nt], 0, 0, 0);
    }
  }
  float dsc0[4], dsc1[4];
#pragma unroll
  for (int r = 0; r < 4; ++r) {
    dsc0[r] = dis[r0 + lk * 4 + r];
    dsc1[r] = dis[r0 + 16 + lk * 4 + r];
  }
  unsigned short* yb = y + (size_t)r0 * C2;
#pragma unroll
  for (int nt = 0; nt < 2; ++nt)
#pragma unroll
    for (int r = 0; r < 4; ++r) {
      yb[(size_t)(lk * 4 + r) * C2 + nt * 16 + lr] = f2b(acc[0][nt][r] * dsc0[r]);
      yb[(size_t)(16 + lk * 4 + r) * C2 + nt * 16 + lr] = f2b(acc[1][nt][r] * dsc1[r]);
    }
}

// ---------------- gather2: 8 streams x 8 lanes x ushort4 (round-6 shape) -----
__global__ __launch_bounds__(256) void k_gather2(const unsigned* __restrict__ off, int n, int E,
                                                 const int* __restrict__ srcbin,
                                                 const float* __restrict__ dis,
                                                 const unsigned short* __restrict__ xw,
                                                 const float* __restrict__ b2,
                                                 float* __restrict__ out) {
  const int w = blockIdx.x * 4 + (threadIdx.x >> 6);
  if (w >= n) return;
  const int lane = threadIdx.x & 63;
  const int c4 = (lane & 7) * 4;  // column group
  const int st = lane >> 3;       // edge stream 0..7
  const float dd = dis[w];
  const unsigned beg = off[w];
  const unsigned end = (w + 1 < n) ? off[w + 1] : (unsigned)E;

  float a0 = 0.f, a1 = 0.f, a2 = 0.f, a3 = 0.f;
  float e0 = 0.f, e1 = 0.f, e2 = 0.f, e3 = 0.f;
  if (st == 0) {  // self-loop (pre-scaled)
    ushort4v u = *reinterpret_cast<const ushort4v*>(xw + (size_t)w * C2 + c4);
    a0 = b2f(u[0]); a1 = b2f(u[1]); a2 = b2f(u[2]); a3 = b2f(u[3]);
  }
  unsigned p = beg + st;
  for (; p + 8 < end; p += 16) {  // x2 unroll per stream
    int s0 = srcbin[p];
    int s1 = srcbin[p + 8];
    ushort4v u0 = *reinterpret_cast<const ushort4v*>(xw + (size_t)s0 * C2 + c4);
    ushort4v u1 = *reinterpret_cast<const ushort4v*>(xw + (size_t)s1 * C2 + c4);
    a0 += b2f(u0[0]); a1 += b2f(u0[1]); a2 += b2f(u0[2]); a3 += b2f(u0[3]);
    e0 += b2f(u1[0]); e1 += b2f(u1[1]); e2 += b2f(u1[2]); e3 += b2f(u1[3]);
  }
  if (p < end) {
    int s0 = srcbin[p];
    ushort4v u0 = *reinterpret_cast<const ushort4v*>(xw + (size_t)s0 * C2 + c4);
    a0 += b2f(u0[0]); a1 += b2f(u0[1]); a2 += b2f(u0[2]); a3 += b2f(u0[3]);
  }
  a0 += e0; a1 += e1; a2 += e2; a3 += e3;
  a0 += __shfl_xor(a0, 8, 64);  a1 += __shfl_xor(a1, 8, 64);
  a2 += __shfl_xor(a2, 8, 64);  a3 += __shfl_xor(a3, 8, 64);
  a0 += __shfl_xor(a0, 16, 64); a1 += __shfl_xor(a1, 16, 64);
  a2 += __shfl_xor(a2, 16, 64); a3 += __shfl_xor(a3, 16, 64);
  a0 += __shfl_xor(a0, 32, 64); a1 += __shfl_xor(a1, 32, 64);
  a2 += __shfl_xor(a2, 32, 64); a3 += __shfl_xor(a3, 32, 64);
  if (st == 0) {
    float4 bb = *reinterpret_cast<const float4*>(b2 + c4);
    float4 o;
    o.x = fmaf(a0, dd, bb.x);
    o.y = fmaf(a1, dd, bb.y);
    o.z = fmaf(a2, dd, bb.z);
    o.w = fmaf(a3, dd, bb.w);
    *reinterpret_cast<float4*>(out + (size_t)w * C2 + c4) = o;
  }
}

// ---------------- launch -----------------------------------------------------
extern "C" void kernel_launch(void* const* d_in, const int* in_sizes, int n_in,
                              void* d_out, int out_size, void* d_ws, size_t ws_size,
                              hipStream_t stream) {
  const float* x  = (const float*)d_in[0];
  const int*   ei = (const int*)d_in[1];
  const float* W1 = (const float*)d_in[2];
  const float* b1 = (const float*)d_in[3];
  const float* W2 = (const float*)d_in[4];
  const float* b2 = (const float*)d_in[5];
  float* out = (float*)d_out;

  const int n = in_sizes[0] / F1;   // 100000
  const int E = in_sizes[1] / 2;    // 1600000
  const int nb = (n + 255) >> BSH2; // 391 buckets (<= 512)

  char* ws = (char*)d_ws;
  size_t woff = 0;
  auto take = [&](size_t bytes) -> void* {
    void* p = ws + woff;
    woff += (bytes + 255) & ~(size_t)255;
    return p;
  };
  float*          dis   = (float*)take((size_t)n * 4);
  unsigned*       off   = (unsigned*)take((size_t)n * 4);
  // zeroed region: bar[8] + bcnt[nb] (single memset covers both)
  unsigned*       zblk  = (unsigned*)take(32 + (size_t)nb * 4);
  unsigned*       bar   = zblk;
  unsigned*       bcnt  = zblk + 8;
  unsigned*       bo    = (unsigned*)take((size_t)nb * 4);
  unsigned*       gcnt  = (unsigned*)take((size_t)NBLK * nb * 4);
  unsigned short* wbt1  = (unsigned short*)take((size_t)H1 * F1 * 2);  // 32 KB
  unsigned short* wbt2  = (unsigned short*)take((size_t)C2 * H1 * 2);  // 4 KB
  int*            srcbin = (int*)take((size_t)E * 4);
  // big region: ebuf (E*4) aliases xw1 (n*H1*2); ebuf dead before gemm1 writes.
  char*           big   = (char*)take((size_t)E * 4 > (size_t)n * H1 * 2 ? (size_t)E * 4
                                                                          : (size_t)n * H1 * 2);
  unsigned*       ebuf = (unsigned*)big;
  unsigned short* xw1  = (unsigned short*)big;
  unsigned short* h    = (unsigned short*)take((size_t)n * H1 * 2);
  unsigned short* xw2  = (unsigned short*)take((size_t)n * C2 * 2);
  (void)ws_size;

  const int ntiles = (n + 127) / 128;
  const int chunk = (((E + NBLK - 1) / NBLK) + 255) & ~255;

  hipMemsetAsync(zblk, 0, 32 + (size_t)nb * 4, stream);
  k_csr<<<NBLK, 256, 0, stream>>>(ei, E, W1, W2, wbt1, wbt2, gcnt, bcnt, bo, bar,
                                  ebuf, off, dis, srcbin, nb, n, chunk);

  k_gemm1<<<ntiles, 256, 0, stream>>>(x, wbt1, dis, xw1, n);
  k_gather1<<<(n + 3) / 4, 256, 0, stream>>>(off, n, E, srcbin, dis, xw1, b1, h);

  k_gemm2<<<ntiles, 256, 0, stream>>>(h, wbt2, dis, xw2, n);
  k_gather2<<<(n + 3) / 4, 256, 0, stream>>>(off, n, E, srcbin, dis, xw2, b2, out);
}

// Round 17
// 238.220 us; speedup vs baseline: 1.0019x; 1.0019x over previous
//
#include <hip/hip_runtime.h>
#include <hip/hip_bf16.h>

static constexpr int F1 = 256;   // input features
static constexpr int H1 = 64;    // hidden dim
static constexpr int C2 = 32;    // output classes
static constexpr int BSH2 = 8;   // bucket shift: 256 nodes per bucket
static constexpr int NBLK = 128; // persistent CSR blocks (== threads in prefix phase)

typedef __attribute__((ext_vector_type(8))) short short8;
typedef __attribute__((ext_vector_type(4))) float f32x4;
typedef __attribute__((ext_vector_type(4))) unsigned short ushort4v;

__device__ __forceinline__ unsigned short f2b(float f) {
  __hip_bfloat16 h = __float2bfloat16(f);
  unsigned short u;
  __builtin_memcpy(&u, &h, 2);
  return u;
}
__device__ __forceinline__ float b2f(unsigned short u) {
  return __uint_as_float(((unsigned)u) << 16);
}

// ---------------- edge-index access (robust to int32 or int64 storage) -----
__device__ __forceinline__ int ld_src(const int* __restrict__ ei, int E, int e, bool is64) {
  return is64 ? ei[2 * (size_t)e] : ei[e];
}
__device__ __forceinline__ int ld_dst(const int* __restrict__ ei, int E, int e, bool is64) {
  return is64 ? ei[2 * ((size_t)E + (size_t)e)] : ei[(size_t)E + (size_t)e];
}

// ---------------- grid-wide spin barrier (128 co-resident blocks) -----------
// bar[idx*2] = arrival counter, bar[idx*2+1] = release flag; both zeroed by
// hipMemsetAsync before every launch (replay-safe, poison-safe).
__device__ __forceinline__ void gsync(unsigned* bar, int idx, unsigned nblk) {
  __syncthreads();
  if (threadIdx.x == 0) {
    __threadfence();
    unsigned prev = atomicAdd(&bar[idx * 2], 1u);
    if (prev == nblk - 1u) {
      atomicExch(&bar[idx * 2 + 1], 1u);
    } else {
      while (atomicAdd(&bar[idx * 2 + 1], 0u) == 0u) {
        __builtin_amdgcn_s_sleep(2);
      }
    }
    __threadfence();
  }
  __syncthreads();
}

// ---------------- fused CSR build: wconv + hist + scans + partition + bin ---
__global__ __launch_bounds__(256) void k_csr(const int* __restrict__ ei, int E,
                                             const float* __restrict__ W1,
                                             const float* __restrict__ W2,
                                             unsigned short* __restrict__ wbt1,
                                             unsigned short* __restrict__ wbt2,
                                             unsigned* __restrict__ gcnt,
                                             unsigned* __restrict__ bcnt,
                                             unsigned* __restrict__ bo,
                                             unsigned* __restrict__ bar,
                                             unsigned* __restrict__ ebuf,
                                             unsigned* __restrict__ off,
                                             float* __restrict__ dis,
                                             int* __restrict__ srcbin,
                                             int nb, int n, int chunk) {
  __shared__ unsigned lhist[512];     // hist / partB bases
  __shared__ unsigned ldeg[256], loff[256], ts[256];
  __shared__ unsigned wsum_[4];
  __shared__ int s_is64;
  const int tid = threadIdx.x;
  const int blk = blockIdx.x;
  const int base = blk * chunk;
  const int bend = min(E, base + chunk);

  // ---- phase 0a: weight convert+transpose (one-time, split across blocks)
  {
    int gidx = blk * 256 + tid;
    if (gidx < 64 * 256) {
      int c = gidx >> 8, k = gidx & 255;
      wbt1[gidx] = f2b(W1[k * 64 + c]);
    }
    int g2 = gidx - 64 * 256;
    if (g2 >= 0 && g2 < 32 * 64) {
      int c = g2 >> 6, k = g2 & 63;
      wbt2[g2] = f2b(W2[k * 32 + c]);
    }
  }

  // ---- phase 0b: int64 detect (kept in register for later phases)
  if (tid == 0) s_is64 = 1;
  __syncthreads();
  {
    int nz = 0;
    for (int i = tid; i < 2048; i += 256) nz |= (ei[2 * i + 1] != 0);
    if (nz) s_is64 = 0;  // benign race
  }
  __syncthreads();
  const bool is64 = s_is64 != 0;

  // ---- phase 0c: per-(block,bucket) histogram + global bucket totals
  for (int i = tid; i < nb; i += 256) lhist[i] = 0;
  __syncthreads();
  for (int e = base + tid; e < bend; e += 256) {
    int d = ld_dst(ei, E, e, is64);
    atomicAdd(&lhist[d >> BSH2], 1u);
  }
  __syncthreads();
  for (int i = tid; i < nb; i += 256) {
    unsigned v = lhist[i];
    gcnt[(size_t)blk * nb + i] = v;
    if (v) atomicAdd(&bcnt[i], v);  // bcnt zeroed by memset
  }
  gsync(bar, 0, NBLK);

  // ---- phase 1: per-bucket exclusive prefix over blocks  (+ block 0: bo scan)
  {
    const int iters = (nb + NBLK - 1) / NBLK;
    for (int it = 0; it < iters; ++it) {
      int b = blk + it * NBLK;
      bool act = (tid < NBLK) && (b < nb);
      unsigned v = act ? gcnt[(size_t)tid * nb + b] : 0u;
      unsigned s = v;
#pragma unroll
      for (int o = 1; o < 64; o <<= 1) {
        unsigned u = __shfl_up(s, o, 64);
        if ((tid & 63) >= o) s += u;
      }
      if (tid == 63) wsum_[0] = s;
      __syncthreads();
      if (act && tid >= 64) s += wsum_[0];
      if (act) gcnt[(size_t)tid * nb + b] = s - v;  // block's base within bucket
      __syncthreads();
    }
    if (blk == 0) {  // exclusive scan of bucket totals -> bo (nb <= 512)
      unsigned l0 = (2 * tid + 0 < nb) ? bcnt[2 * tid + 0] : 0u;
      unsigned l1 = (2 * tid + 1 < nb) ? bcnt[2 * tid + 1] : 0u;
      ts[tid] = l0 + l1;
      __syncthreads();
      for (int o = 1; o < 256; o <<= 1) {
        unsigned v = ts[tid];
        unsigned add = (tid >= o) ? ts[tid - o] : 0u;
        __syncthreads();
        ts[tid] = v + add;
        __syncthreads();
      }
      unsigned prefix = (tid > 0) ? ts[tid - 1] : 0u;
      if (2 * tid + 0 < nb) bo[2 * tid + 0] = prefix;
      if (2 * tid + 1 < nb) bo[2 * tid + 1] = prefix + l0;
    }
  }
  gsync(bar, 1, NBLK);

  // ---- phase 2: partition pass B — packed (d_local<<24 | src) words
  for (int i = tid; i < nb; i += 256) lhist[i] = bo[i] + gcnt[(size_t)blk * nb + i];
  __syncthreads();
  for (int e = base + tid; e < bend; e += 256) {
    int s = ld_src(ei, E, e, is64);
    int d = ld_dst(ei, E, e, is64);
    unsigned pos = atomicAdd(&lhist[d >> BSH2], 1u);
    ebuf[pos] = ((unsigned)(d & 255) << 24) | (unsigned)s;
  }
  gsync(bar, 2, NBLK);

  // ---- phase 3: per-bucket CSR finish (deg, dis, off, binning)
  for (int b = blk; b < nb; b += NBLK) {
    const int node0 = b << BSH2;
    const int nn = min(256, n - node0);
    const unsigned beg = bo[b];
    const unsigned end = (b + 1 < nb) ? bo[b + 1] : (unsigned)E;
    ldeg[tid] = 0;
    __syncthreads();
    for (unsigned p = beg + tid; p < end; p += 256) {
      atomicAdd(&ldeg[ebuf[p] >> 24], 1u);
    }
    __syncthreads();
    unsigned v = ldeg[tid];
    unsigned s = v;
#pragma unroll
    for (int o = 1; o < 64; o <<= 1) {
      unsigned t = __shfl_up(s, o, 64);
      if ((tid & 63) >= o) s += t;
    }
    if ((tid & 63) == 63) wsum_[tid >> 6] = s;
    __syncthreads();
    unsigned add = 0;
    for (int w = 0; w < (tid >> 6); ++w) add += wsum_[w];
    s += add;
    loff[tid] = s - v;
    if (tid < nn) {
      off[node0 + tid] = beg + (s - v);
      dis[node0 + tid] = 1.0f / sqrtf((float)(v + 1u));  // + self-loop
    }
    ldeg[tid] = 0;  // reuse as fill counters
    __syncthreads();
    for (unsigned p = beg + tid; p < end; p += 256) {
      unsigned e = ebuf[p];
      unsigned li = e >> 24;
      unsigned pos = loff[li] + atomicAdd(&ldeg[li], 1u);
      srcbin[beg + pos] = (int)(e & 0xFFFFFFu);
    }
    __syncthreads();  // protect ldeg/loff reuse across loop iterations
  }
}

// ---------------- GEMM1 (MFMA): xw1' = dis .* (x @ W1), bf16 out -------------
// LDS staged by straight float4 COPY of pre-transposed wbt1 (no convert, no
// transpose, no bank conflicts). Padded [64][264] rows for conflict-free reads.
__global__ __launch_bounds__(256) void k_gemm1(const float* __restrict__ x,
                                               const unsigned short* __restrict__ wbt,
                                               const float* __restrict__ dis,
                                               unsigned short* __restrict__ y,
                                               int n) {
  __shared__ __align__(16) unsigned short wl[64][264];
  const int tid = threadIdx.x;
  for (int i = tid; i < 64 * 32; i += 256) {  // 2048 x 16B copies
    int row = i >> 5, c8 = (i & 31) * 8;
    *reinterpret_cast<float4*>(&wl[row][c8]) =
        *reinterpret_cast<const float4*>(wbt + (size_t)row * F1 + c8);
  }
  __syncthreads();

  const int wq = tid >> 6, l = tid & 63;
  const int lr = l & 15, lk = l >> 4;
  const int r0 = blockIdx.x * 128 + wq * 32;
  if (r0 >= n) return;  // n % 32 == 0 -> surviving waves are full

  f32x4 acc[2][4] = {};
  const float* xr0 = x + (size_t)(r0 + lr) * F1;
  const float* xr1 = xr0 + (size_t)16 * F1;
#pragma unroll
  for (int kc = 0; kc < 8; ++kc) {
    const int kb = kc * 32 + lk * 8;
    float4 p0 = *reinterpret_cast<const float4*>(xr0 + kb);
    float4 p1 = *reinterpret_cast<const float4*>(xr0 + kb + 4);
    float4 q0 = *reinterpret_cast<const float4*>(xr1 + kb);
    float4 q1 = *reinterpret_cast<const float4*>(xr1 + kb + 4);
    short8 a0, a1;
    a0[0] = f2b(p0.x); a0[1] = f2b(p0.y); a0[2] = f2b(p0.z); a0[3] = f2b(p0.w);
    a0[4] = f2b(p1.x); a0[5] = f2b(p1.y); a0[6] = f2b(p1.z); a0[7] = f2b(p1.w);
    a1[0] = f2b(q0.x); a1[1] = f2b(q0.y); a1[2] = f2b(q0.z); a1[3] = f2b(q0.w);
    a1[4] = f2b(q1.x); a1[5] = f2b(q1.y); a1[6] = f2b(q1.z); a1[7] = f2b(q1.w);
#pragma unroll
    for (int nt = 0; nt < 4; ++nt) {
      short8 bb = *reinterpret_cast<const short8*>(&wl[nt * 16 + lr][kb]);
      acc[0][nt] = __builtin_amdgcn_mfma_f32_16x16x32_bf16(a0, bb, acc[0][nt], 0, 0, 0);
      acc[1][nt] = __builtin_amdgcn_mfma_f32_16x16x32_bf16(a1, bb, acc[1][nt], 0, 0, 0);
    }
  }
  float dsc0[4], dsc1[4];
#pragma unroll
  for (int r = 0; r < 4; ++r) {
    dsc0[r] = dis[r0 + lk * 4 + r];
    dsc1[r] = dis[r0 + 16 + lk * 4 + r];
  }
  unsigned short* yb = y + (size_t)r0 * H1;
#pragma unroll
  for (int nt = 0; nt < 4; ++nt)
#pragma unroll
    for (int r = 0; r < 4; ++r) {
      yb[(size_t)(lk * 4 + r) * H1 + nt * 16 + lr] = f2b(acc[0][nt][r] * dsc0[r]);
      yb[(size_t)(16 + lk * 4 + r) * H1 + nt * 16 + lr] = f2b(acc[1][nt][r] * dsc1[r]);
    }
}

// ---------------- gather1: 4 streams x 16 lanes x ushort4 (round-6 shape) ----
__global__ __launch_bounds__(256) void k_gather1(const unsigned* __restrict__ off, int n, int E,
                                                 const int* __restrict__ srcbin,
                                                 const float* __restrict__ dis,
                                                 const unsigned short* __restrict__ xw,
                                                 const float* __restrict__ b1,
                                                 unsigned short* __restrict__ h) {
  const int w = blockIdx.x * 4 + (threadIdx.x >> 6);
  if (w >= n) return;
  const int lane = threadIdx.x & 63;
  const int c4 = (lane & 15) * 4;  // column group
  const int st = lane >> 4;        // edge stream 0..3
  const float dd = dis[w];
  const unsigned beg = off[w];
  const unsigned end = (w + 1 < n) ? off[w + 1] : (unsigned)E;

  float a0 = 0.f, a1 = 0.f, a2 = 0.f, a3 = 0.f;
  float e0 = 0.f, e1 = 0.f, e2 = 0.f, e3 = 0.f;
  if (st == 0) {  // self-loop (pre-scaled)
    ushort4v u = *reinterpret_cast<const ushort4v*>(xw + (size_t)w * H1 + c4);
    a0 = b2f(u[0]); a1 = b2f(u[1]); a2 = b2f(u[2]); a3 = b2f(u[3]);
  }
  unsigned p = beg + st;
  for (; p + 4 < end; p += 8) {  // x2 unroll per stream
    int s0 = srcbin[p];
    int s1 = srcbin[p + 4];
    ushort4v u0 = *reinterpret_cast<const ushort4v*>(xw + (size_t)s0 * H1 + c4);
    ushort4v u1 = *reinterpret_cast<const ushort4v*>(xw + (size_t)s1 * H1 + c4);
    a0 += b2f(u0[0]); a1 += b2f(u0[1]); a2 += b2f(u0[2]); a3 += b2f(u0[3]);
    e0 += b2f(u1[0]); e1 += b2f(u1[1]); e2 += b2f(u1[2]); e3 += b2f(u1[3]);
  }
  if (p < end) {
    int s0 = srcbin[p];
    ushort4v u0 = *reinterpret_cast<const ushort4v*>(xw + (size_t)s0 * H1 + c4);
    a0 += b2f(u0[0]); a1 += b2f(u0[1]); a2 += b2f(u0[2]); a3 += b2f(u0[3]);
  }
  a0 += e0; a1 += e1; a2 += e2; a3 += e3;
  a0 += __shfl_xor(a0, 16, 64); a1 += __shfl_xor(a1, 16, 64);
  a2 += __shfl_xor(a2, 16, 64); a3 += __shfl_xor(a3, 16, 64);
  a0 += __shfl_xor(a0, 32, 64); a1 += __shfl_xor(a1, 32, 64);
  a2 += __shfl_xor(a2, 32, 64); a3 += __shfl_xor(a3, 32, 64);
  if (st == 0) {
    float4 bb = *reinterpret_cast<const float4*>(b1 + c4);
    ushort4v hv;
    hv[0] = f2b(fmaxf(fmaf(a0, dd, bb.x), 0.0f));
    hv[1] = f2b(fmaxf(fmaf(a1, dd, bb.y), 0.0f));
    hv[2] = f2b(fmaxf(fmaf(a2, dd, bb.z), 0.0f));
    hv[3] = f2b(fmaxf(fmaf(a3, dd, bb.w), 0.0f));
    *reinterpret_cast<ushort4v*>(h + (size_t)w * H1 + c4) = hv;
  }
}

// ---------------- GEMM2 (MFMA, no LDS): xw2' = dis .* (h @ W2) ---------------
__global__ __launch_bounds__(256) void k_gemm2(const unsigned short* __restrict__ h,
                                               const unsigned short* __restrict__ wbt,
                                               const float* __restrict__ dis,
                                               unsigned short* __restrict__ y,
                                               int n) {
  const int tid = threadIdx.x;
  const int wq = tid >> 6, l = tid & 63;
  const int lr = l & 15, lk = l >> 4;
  const int r0 = blockIdx.x * 128 + wq * 32;
  if (r0 >= n) return;

  short8 bfrag[2][2];
#pragma unroll
  for (int kc = 0; kc < 2; ++kc)
#pragma unroll
    for (int nt = 0; nt < 2; ++nt)
      bfrag[kc][nt] =
          *reinterpret_cast<const short8*>(wbt + (size_t)(nt * 16 + lr) * H1 + kc * 32 + lk * 8);

  f32x4 acc[2][2] = {};
  const unsigned short* h0 = h + (size_t)(r0 + lr) * H1;
  const unsigned short* h1 = h0 + (size_t)16 * H1;
#pragma unroll
  for (int kc = 0; kc < 2; ++kc) {
    const int kb = kc * 32 + lk * 8;
    short8 a0 = *reinterpret_cast<const short8*>(h0 + kb);
    short8 a1 = *reinterpret_cast<const short8*>(h1 + kb);
#pragma unroll
    for (int nt = 0; nt < 2; ++nt) {
      acc[0][nt] = __builtin_amdgcn_mfma_f32_16x16x32_bf16(a0, bfrag[kc][nt], acc[0][nt], 0, 0, 0);
      acc[1][nt] = __builtin_amdgcn_mfma_f32_16x16x32_bf16(a1, bfrag[kc][nt], acc[1][nt], 0, 0, 0);
    }
  }
  float dsc0[4], dsc1[4];
#pragma unroll
  for (int r = 0; r < 4; ++r) {
    dsc0[r] = dis[r0 + lk * 4 + r];
    dsc1[r] = dis[r0 + 16 + lk * 4 + r];
  }
  unsigned short* yb = y + (size_t)r0 * C2;
#pragma unroll
  for (int nt = 0; nt < 2; ++nt)
#pragma unroll
    for (int r = 0; r < 4; ++r) {
      yb[(size_t)(lk * 4 + r) * C2 + nt * 16 + lr] = f2b(acc[0][nt][r] * dsc0[r]);
      yb[(size_t)(16 + lk * 4 + r) * C2 + nt * 16 + lr] = f2b(acc[1][nt][r] * dsc1[r]);
    }
}

// ---------------- gather2: 8 streams x 8 lanes x ushort4 (round-6 shape) -----
__global__ __launch_bounds__(256) void k_gather2(const unsigned* __restrict__ off, int n, int E,
                                                 const int* __restrict__ srcbin,
                                                 const float* __restrict__ dis,
                                                 const unsigned short* __restrict__ xw,
                                                 const float* __restrict__ b2,
                                                 float* __restrict__ out) {
  const int w = blockIdx.x * 4 + (threadIdx.x >> 6);
  if (w >= n) return;
  const int lane = threadIdx.x & 63;
  const int c4 = (lane & 7) * 4;  // column group
  const int st = lane >> 3;       // edge stream 0..7
  const float dd = dis[w];
  const unsigned beg = off[w];
  const unsigned end = (w + 1 < n) ? off[w + 1] : (unsigned)E;

  float a0 = 0.f, a1 = 0.f, a2 = 0.f, a3 = 0.f;
  float e0 = 0.f, e1 = 0.f, e2 = 0.f, e3 = 0.f;
  if (st == 0) {  // self-loop (pre-scaled)
    ushort4v u = *reinterpret_cast<const ushort4v*>(xw + (size_t)w * C2 + c4);
    a0 = b2f(u[0]); a1 = b2f(u[1]); a2 = b2f(u[2]); a3 = b2f(u[3]);
  }
  unsigned p = beg + st;
  for (; p + 8 < end; p += 16) {  // x2 unroll per stream
    int s0 = srcbin[p];
    int s1 = srcbin[p + 8];
    ushort4v u0 = *reinterpret_cast<const ushort4v*>(xw + (size_t)s0 * C2 + c4);
    ushort4v u1 = *reinterpret_cast<const ushort4v*>(xw + (size_t)s1 * C2 + c4);
    a0 += b2f(u0[0]); a1 += b2f(u0[1]); a2 += b2f(u0[2]); a3 += b2f(u0[3]);
    e0 += b2f(u1[0]); e1 += b2f(u1[1]); e2 += b2f(u1[2]); e3 += b2f(u1[3]);
  }
  if (p < end) {
    int s0 = srcbin[p];
    ushort4v u0 = *reinterpret_cast<const ushort4v*>(xw + (size_t)s0 * C2 + c4);
    a0 += b2f(u0[0]); a1 += b2f(u0[1]); a2 += b2f(u0[2]); a3 += b2f(u0[3]);
  }
  a0 += e0; a1 += e1; a2 += e2; a3 += e3;
  a0 += __shfl_xor(a0, 8, 64);  a1 += __shfl_xor(a1, 8, 64);
  a2 += __shfl_xor(a2, 8, 64);  a3 += __shfl_xor(a3, 8, 64);
  a0 += __shfl_xor(a0, 16, 64); a1 += __shfl_xor(a1, 16, 64);
  a2 += __shfl_xor(a2, 16, 64); a3 += __shfl_xor(a3, 16, 64);
  a0 += __shfl_xor(a0, 32, 64); a1 += __shfl_xor(a1, 32, 64);
  a2 += __shfl_xor(a2, 32, 64); a3 += __shfl_xor(a3, 32, 64);
  if (st == 0) {
    float4 bb = *reinterpret_cast<const float4*>(b2 + c4);
    float4 o;
    o.x = fmaf(a0, dd, bb.x);
    o.y = fmaf(a1, dd, bb.y);
    o.z = fmaf(a2, dd, bb.z);
    o.w = fmaf(a3, dd, bb.w);
    *reinterpret_cast<float4*>(out + (size_t)w * C2 + c4) = o;
  }
}

// ---------------- launch -----------------------------------------------------
extern "C" void kernel_launch(void* const* d_in, const int* in_sizes, int n_in,
                              void* d_out, int out_size, void* d_ws, size_t ws_size,
                              hipStream_t stream) {
  const float* x  = (const float*)d_in[0];
  const int*   ei = (const int*)d_in[1];
  const float* W1 = (const float*)d_in[2];
  const float* b1 = (const float*)d_in[3];
  const float* W2 = (const float*)d_in[4];
  const float* b2 = (const float*)d_in[5];
  float* out = (float*)d_out;

  const int n = in_sizes[0] / F1;   // 100000
  const int E = in_sizes[1] / 2;    // 1600000
  const int nb = (n + 255) >> BSH2; // 391 buckets (<= 512)

  char* ws = (char*)d_ws;
  size_t woff = 0;
  auto take = [&](size_t bytes) -> void* {
    void* p = ws + woff;
    woff += (bytes + 255) & ~(size_t)255;
    return p;
  };
  float*          dis   = (float*)take((size_t)n * 4);
  unsigned*       off   = (unsigned*)take((size_t)n * 4);
  // zeroed region: bar[8] + bcnt[nb] (single memset covers both)
  unsigned*       zblk  = (unsigned*)take(32 + (size_t)nb * 4);
  unsigned*       bar   = zblk;
  unsigned*       bcnt  = zblk + 8;
  unsigned*       bo    = (unsigned*)take((size_t)nb * 4);
  unsigned*       gcnt  = (unsigned*)take((size_t)NBLK * nb * 4);
  unsigned short* wbt1  = (unsigned short*)take((size_t)H1 * F1 * 2);  // 32 KB
  unsigned short* wbt2  = (unsigned short*)take((size_t)C2 * H1 * 2);  // 4 KB
  int*            srcbin = (int*)take((size_t)E * 4);
  // big region: ebuf (E*4) aliases xw1 (n*H1*2); ebuf dead before gemm1 writes.
  char*           big   = (char*)take((size_t)E * 4 > (size_t)n * H1 * 2 ? (size_t)E * 4
                                                                          : (size_t)n * H1 * 2);
  unsigned*       ebuf = (unsigned*)big;
  unsigned short* xw1  = (unsigned short*)big;
  unsigned short* h    = (unsigned short*)take((size_t)n * H1 * 2);
  unsigned short* xw2  = (unsigned short*)take((size_t)n * C2 * 2);
  (void)ws_size;

  const int ntiles = (n + 127) / 128;
  const int chunk = (((E + NBLK - 1) / NBLK) + 255) & ~255;

  hipMemsetAsync(zblk, 0, 32 + (size_t)nb * 4, stream);
  k_csr<<<NBLK, 256, 0, stream>>>(ei, E, W1, W2, wbt1, wbt2, gcnt, bcnt, bo, bar,
                                  ebuf, off, dis, srcbin, nb, n, chunk);

  k_gemm1<<<ntiles, 256, 0, stream>>>(x, wbt1, dis, xw1, n);
  k_gather1<<<(n + 3) / 4, 256, 0, stream>>>(off, n, E, srcbin, dis, xw1, b1, h);

  k_gemm2<<<ntiles, 256, 0, stream>>>(h, wbt2, dis, xw2, n);
  k_gather2<<<(n + 3) / 4, 256, 0, stream>>>(off, n, E, srcbin, dis, xw2, b2, out);
}

// Round 18
// 186.563 us; speedup vs baseline: 1.2794x; 1.2769x over previous
//
#include <hip/hip_runtime.h>
#include <hip/hip_bf16.h>

static constexpr int F1 = 256;   // input features
static constexpr int H1 = 64;    // hidden dim
static constexpr int C2 = 32;    // output classes
static constexpr int BSH2 = 8;   // bucket shift: 256 nodes per bucket
static constexpr int NBLK = 128; // partition blocks

typedef __attribute__((ext_vector_type(8))) short short8;
typedef __attribute__((ext_vector_type(4))) float f32x4;
typedef __attribute__((ext_vector_type(4))) unsigned short ushort4v;

__device__ __forceinline__ unsigned short f2b(float f) {
  __hip_bfloat16 h = __float2bfloat16(f);
  unsigned short u;
  __builtin_memcpy(&u, &h, 2);
  return u;
}
__device__ __forceinline__ float b2f(unsigned short u) {
  return __uint_as_float(((unsigned)u) << 16);
}

// ---------------- edge-index access (robust to int32 or int64 storage) -----
__device__ __forceinline__ int ld_src(const int* __restrict__ ei, int E, int e, bool is64) {
  return is64 ? ei[2 * (size_t)e] : ei[e];
}
__device__ __forceinline__ int ld_dst(const int* __restrict__ ei, int E, int e, bool is64) {
  return is64 ? ei[2 * ((size_t)E + (size_t)e)] : ei[(size_t)E + (size_t)e];
}

// per-block int64-layout detection: odd 32-bit words all zero => int64.
__device__ __forceinline__ bool detect64(const int* __restrict__ ei, int tid,
                                         int* s_is64) {
  if (tid == 0) *s_is64 = 1;
  __syncthreads();
  int nz = 0;
  for (int i = tid; i < 2048; i += 256) nz |= (ei[2 * i + 1] != 0);
  if (nz) *s_is64 = 0;  // benign race
  __syncthreads();
  return *s_is64 != 0;
}

// ---------------- one-time weight convert+transpose to bf16 ------------------
// wbt1[c][k] = bf16(W1[k][c])  (64 x 256);  wbt2[c][k] = bf16(W2[k][c]) (32 x 64)
__global__ __launch_bounds__(256) void k_wconv(const float* __restrict__ W1,
                                               const float* __restrict__ W2,
                                               unsigned short* __restrict__ wbt1,
                                               unsigned short* __restrict__ wbt2) {
  int tid = blockIdx.x * 256 + threadIdx.x;
  if (tid < 64 * 256) {
    int c = tid >> 8, k = tid & 255;
    wbt1[tid] = f2b(W1[k * 64 + c]);
  }
  if (tid < 32 * 64) {
    int c = tid >> 6, k = tid & 63;
    wbt2[tid] = f2b(W2[k * 32 + c]);
  }
}

// ---------------- partition pass A: per-(block,bucket) histogram -------------
__global__ __launch_bounds__(256) void k_partA(const int* __restrict__ ei, int E,
                                               unsigned* __restrict__ gcnt,
                                               int nb, int chunk) {
  __shared__ unsigned lhist[512];
  __shared__ int s_is64;
  const bool is64 = detect64(ei, threadIdx.x, &s_is64);
  const int base = blockIdx.x * chunk;
  const int end = min(E, base + chunk);
  for (int i = threadIdx.x; i < nb; i += 256) lhist[i] = 0;
  __syncthreads();
  for (int e = base + threadIdx.x; e < end; e += 256) {
    int d = ld_dst(ei, E, e, is64);
    atomicAdd(&lhist[d >> BSH2], 1u);
  }
  __syncthreads();
  unsigned* g = gcnt + (size_t)blockIdx.x * nb;
  for (int i = threadIdx.x; i < nb; i += 256) g[i] = lhist[i];
}

// ---------------- per-bucket prefix over blocks (grid = nb, 128 thr) ---------
__global__ __launch_bounds__(128) void k_bscan(unsigned* __restrict__ gcnt,
                                               unsigned* __restrict__ bcnt, int nb) {
  __shared__ unsigned ws;
  const int b = blockIdx.x;
  const int t = threadIdx.x;  // block index 0..127
  unsigned v = gcnt[(size_t)t * nb + b];
  unsigned s = v;
#pragma unroll
  for (int o = 1; o < 64; o <<= 1) {
    unsigned u = __shfl_up(s, o, 64);
    if ((t & 63) >= o) s += u;
  }
  if (t == 63) ws = s;
  __syncthreads();
  if (t >= 64) s += ws;
  gcnt[(size_t)t * nb + b] = s - v;  // exclusive prefix (block's base in bucket)
  if (t == 127) bcnt[b] = s;         // bucket total
}

// ---------------- single-block exclusive scan over buckets (nb <= 512) -------
__global__ __launch_bounds__(256) void k_scan_small(const unsigned* __restrict__ bcnt,
                                                    unsigned* __restrict__ bo, int nb) {
  __shared__ unsigned ts[256];
  const int t = threadIdx.x;
  unsigned l0 = (2 * t + 0 < nb) ? bcnt[2 * t + 0] : 0u;
  unsigned l1 = (2 * t + 1 < nb) ? bcnt[2 * t + 1] : 0u;
  ts[t] = l0 + l1;
  __syncthreads();
  for (int o = 1; o < 256; o <<= 1) {
    unsigned v = ts[t];
    unsigned add = (t >= o) ? ts[t - o] : 0u;
    __syncthreads();
    ts[t] = v + add;
    __syncthreads();
  }
  unsigned prefix = (t > 0) ? ts[t - 1] : 0u;
  if (2 * t + 0 < nb) bo[2 * t + 0] = prefix;
  if (2 * t + 1 < nb) bo[2 * t + 1] = prefix + l0;
}

// ---------------- partition pass B: packed (d_local<<24 | src) words ---------
// Requires n < 2^24 (holds: n = 100000).
__global__ __launch_bounds__(256) void k_partB(const int* __restrict__ ei, int E,
                                               const unsigned* __restrict__ bo,
                                               const unsigned* __restrict__ gcnt,
                                               unsigned* __restrict__ ebuf,
                                               int nb, int chunk) {
  __shared__ unsigned gb[512];
  __shared__ int s_is64;
  const bool is64 = detect64(ei, threadIdx.x, &s_is64);
  const int base = blockIdx.x * chunk;
  const int end = min(E, base + chunk);
  const unsigned* g = gcnt + (size_t)blockIdx.x * nb;
  for (int i = threadIdx.x; i < nb; i += 256) gb[i] = bo[i] + g[i];
  __syncthreads();
  for (int e = base + threadIdx.x; e < end; e += 256) {
    int s = ld_src(ei, E, e, is64);
    int d = ld_dst(ei, E, e, is64);
    unsigned pos = atomicAdd(&gb[d >> BSH2], 1u);
    ebuf[pos] = ((unsigned)(d & 255) << 24) | (unsigned)s;
  }
}

// ---------------- per-bucket CSR finish: deg, dis, off, binning — all in LDS -
__global__ __launch_bounds__(256) void k_bucket_csr(const unsigned* __restrict__ bo,
                                                    const unsigned* __restrict__ ebuf,
                                                    int nb, int n, int E,
                                                    unsigned* __restrict__ off,
                                                    float* __restrict__ dis,
                                                    int* __restrict__ srcbin) {
  __shared__ unsigned ldeg[256], loff[256], wsum[4];
  const int b = blockIdx.x;
  const int tid = threadIdx.x;
  const int node0 = b << BSH2;
  const int nn = min(256, n - node0);
  const unsigned beg = bo[b];
  const unsigned end = (b + 1 < nb) ? bo[b + 1] : (unsigned)E;

  ldeg[tid] = 0;
  __syncthreads();
  for (unsigned p = beg + tid; p < end; p += 256) {
    atomicAdd(&ldeg[ebuf[p] >> 24], 1u);
  }
  __syncthreads();
  unsigned v = ldeg[tid];
  unsigned s = v;  // inclusive scan: intra-wave shfl + cross-wave LDS
#pragma unroll
  for (int o = 1; o < 64; o <<= 1) {
    unsigned t = __shfl_up(s, o, 64);
    if ((tid & 63) >= o) s += t;
  }
  if ((tid & 63) == 63) wsum[tid >> 6] = s;
  __syncthreads();
  unsigned add = 0;
  for (int w = 0; w < (tid >> 6); ++w) add += wsum[w];
  s += add;
  loff[tid] = s - v;
  if (tid < nn) {
    off[node0 + tid] = beg + (s - v);
    dis[node0 + tid] = 1.0f / sqrtf((float)(v + 1u));  // + self-loop
  }
  ldeg[tid] = 0;  // reuse as fill counters
  __syncthreads();
  for (unsigned p = beg + tid; p < end; p += 256) {
    unsigned e = ebuf[p];
    unsigned li = e >> 24;
    unsigned pos = loff[li] + atomicAdd(&ldeg[li], 1u);
    srcbin[beg + pos] = (int)(e & 0xFFFFFFu);
  }
}

// ---------------- GEMM1 (MFMA): xw1' = dis .* (x @ W1), bf16 out -------------
// LDS staged by straight float4 COPY of pre-transposed wbt1 (no convert, no
// transpose, no bank conflicts). Padded [64][264] rows for conflict-free reads.
__global__ __launch_bounds__(256) void k_gemm1(const float* __restrict__ x,
                                               const unsigned short* __restrict__ wbt,
                                               const float* __restrict__ dis,
                                               unsigned short* __restrict__ y,
                                               int n) {
  __shared__ __align__(16) unsigned short wl[64][264];
  const int tid = threadIdx.x;
  for (int i = tid; i < 64 * 32; i += 256) {  // 2048 x 16B copies
    int row = i >> 5, c8 = (i & 31) * 8;
    *reinterpret_cast<float4*>(&wl[row][c8]) =
        *reinterpret_cast<const float4*>(wbt + (size_t)row * F1 + c8);
  }
  __syncthreads();

  const int wq = tid >> 6, l = tid & 63;
  const int lr = l & 15, lk = l >> 4;
  const int r0 = blockIdx.x * 128 + wq * 32;
  if (r0 >= n) return;  // n % 32 == 0 -> surviving waves are full

  f32x4 acc[2][4] = {};
  const float* xr0 = x + (size_t)(r0 + lr) * F1;
  const float* xr1 = xr0 + (size_t)16 * F1;
#pragma unroll
  for (int kc = 0; kc < 8; ++kc) {
    const int kb = kc * 32 + lk * 8;
    float4 p0 = *reinterpret_cast<const float4*>(xr0 + kb);
    float4 p1 = *reinterpret_cast<const float4*>(xr0 + kb + 4);
    float4 q0 = *reinterpret_cast<const float4*>(xr1 + kb);
    float4 q1 = *reinterpret_cast<const float4*>(xr1 + kb + 4);
    short8 a0, a1;
    a0[0] = f2b(p0.x); a0[1] = f2b(p0.y); a0[2] = f2b(p0.z); a0[3] = f2b(p0.w);
    a0[4] = f2b(p1.x); a0[5] = f2b(p1.y); a0[6] = f2b(p1.z); a0[7] = f2b(p1.w);
    a1[0] = f2b(q0.x); a1[1] = f2b(q0.y); a1[2] = f2b(q0.z); a1[3] = f2b(q0.w);
    a1[4] = f2b(q1.x); a1[5] = f2b(q1.y); a1[6] = f2b(q1.z); a1[7] = f2b(q1.w);
#pragma unroll
    for (int nt = 0; nt < 4; ++nt) {
      short8 bb = *reinterpret_cast<const short8*>(&wl[nt * 16 + lr][kb]);
      acc[0][nt] = __builtin_amdgcn_mfma_f32_16x16x32_bf16(a0, bb, acc[0][nt], 0, 0, 0);
      acc[1][nt] = __builtin_amdgcn_mfma_f32_16x16x32_bf16(a1, bb, acc[1][nt], 0, 0, 0);
    }
  }
  float dsc0[4], dsc1[4];
#pragma unroll
  for (int r = 0; r < 4; ++r) {
    dsc0[r] = dis[r0 + lk * 4 + r];
    dsc1[r] = dis[r0 + 16 + lk * 4 + r];
  }
  unsigned short* yb = y + (size_t)r0 * H1;
#pragma unroll
  for (int nt = 0; nt < 4; ++nt)
#pragma unroll
    for (int r = 0; r < 4; ++r) {
      yb[(size_t)(lk * 4 + r) * H1 + nt * 16 + lr] = f2b(acc[0][nt][r] * dsc0[r]);
      yb[(size_t)(16 + lk * 4 + r) * H1 + nt * 16 + lr] = f2b(acc[1][nt][r] * dsc1[r]);
    }
}

// ---------------- gather1: 4 streams x 16 lanes x ushort4 (round-6 exact) ----
// h[d] = relu( dis[d] * sum_{s in bin(d) U {d}} xw1'[s] + b1 ), xw1' pre-scaled.
__global__ __launch_bounds__(256) void k_gather1(const unsigned* __restrict__ off, int n, int E,
                                                 const int* __restrict__ srcbin,
                                                 const float* __restrict__ dis,
                                                 const unsigned short* __restrict__ xw,
                                                 const float* __restrict__ b1,
                                                 unsigned short* __restrict__ h) {
  const int w = blockIdx.x * 4 + (threadIdx.x >> 6);
  if (w >= n) return;
  const int lane = threadIdx.x & 63;
  const int c4 = (lane & 15) * 4;  // column group
  const int st = lane >> 4;        // edge stream 0..3
  const float dd = dis[w];
  const unsigned beg = off[w];
  const unsigned end = (w + 1 < n) ? off[w + 1] : (unsigned)E;

  float a0 = 0.f, a1 = 0.f, a2 = 0.f, a3 = 0.f;
  float e0 = 0.f, e1 = 0.f, e2 = 0.f, e3 = 0.f;
  if (st == 0) {  // self-loop (pre-scaled)
    ushort4v u = *reinterpret_cast<const ushort4v*>(xw + (size_t)w * H1 + c4);
    a0 = b2f(u[0]); a1 = b2f(u[1]); a2 = b2f(u[2]); a3 = b2f(u[3]);
  }
  unsigned p = beg + st;
  for (; p + 4 < end; p += 8) {  // x2 unroll per stream
    int s0 = srcbin[p];
    int s1 = srcbin[p + 4];
    ushort4v u0 = *reinterpret_cast<const ushort4v*>(xw + (size_t)s0 * H1 + c4);
    ushort4v u1 = *reinterpret_cast<const ushort4v*>(xw + (size_t)s1 * H1 + c4);
    a0 += b2f(u0[0]); a1 += b2f(u0[1]); a2 += b2f(u0[2]); a3 += b2f(u0[3]);
    e0 += b2f(u1[0]); e1 += b2f(u1[1]); e2 += b2f(u1[2]); e3 += b2f(u1[3]);
  }
  if (p < end) {
    int s0 = srcbin[p];
    ushort4v u0 = *reinterpret_cast<const ushort4v*>(xw + (size_t)s0 * H1 + c4);
    a0 += b2f(u0[0]); a1 += b2f(u0[1]); a2 += b2f(u0[2]); a3 += b2f(u0[3]);
  }
  a0 += e0; a1 += e1; a2 += e2; a3 += e3;
  a0 += __shfl_xor(a0, 16, 64); a1 += __shfl_xor(a1, 16, 64);
  a2 += __shfl_xor(a2, 16, 64); a3 += __shfl_xor(a3, 16, 64);
  a0 += __shfl_xor(a0, 32, 64); a1 += __shfl_xor(a1, 32, 64);
  a2 += __shfl_xor(a2, 32, 64); a3 += __shfl_xor(a3, 32, 64);
  if (st == 0) {
    float4 bb = *reinterpret_cast<const float4*>(b1 + c4);
    ushort4v hv;
    hv[0] = f2b(fmaxf(fmaf(a0, dd, bb.x), 0.0f));
    hv[1] = f2b(fmaxf(fmaf(a1, dd, bb.y), 0.0f));
    hv[2] = f2b(fmaxf(fmaf(a2, dd, bb.z), 0.0f));
    hv[3] = f2b(fmaxf(fmaf(a3, dd, bb.w), 0.0f));
    *reinterpret_cast<ushort4v*>(h + (size_t)w * H1 + c4) = hv;
  }
}

// ---------------- GEMM2 (MFMA, no LDS): xw2' = dis .* (h @ W2) ---------------
// B-fragments register-direct from 4 KB pre-transposed wbt2 (L1 broadcast).
__global__ __launch_bounds__(256) void k_gemm2(const unsigned short* __restrict__ h,
                                               const unsigned short* __restrict__ wbt,
                                               const float* __restrict__ dis,
                                               unsigned short* __restrict__ y,
                                               int n) {
  const int tid = threadIdx.x;
  const int wq = tid >> 6, l = tid & 63;
  const int lr = l & 15, lk = l >> 4;
  const int r0 = blockIdx.x * 128 + wq * 32;
  if (r0 >= n) return;

  short8 bfrag[2][2];
#pragma unroll
  for (int kc = 0; kc < 2; ++kc)
#pragma unroll
    for (int nt = 0; nt < 2; ++nt)
      bfrag[kc][nt] =
          *reinterpret_cast<const short8*>(wbt + (size_t)(nt * 16 + lr) * H1 + kc * 32 + lk * 8);

  f32x4 acc[2][2] = {};
  const unsigned short* h0 = h + (size_t)(r0 + lr) * H1;
  const unsigned short* h1 = h0 + (size_t)16 * H1;
#pragma unroll
  for (int kc = 0; kc < 2; ++kc) {
    const int kb = kc * 32 + lk * 8;
    short8 a0 = *reinterpret_cast<const short8*>(h0 + kb);
    short8 a1 = *reinterpret_cast<const short8*>(h1 + kb);
#pragma unroll
    for (int nt = 0; nt < 2; ++nt) {
      acc[0][nt] = __builtin_amdgcn_mfma_f32_16x16x32_bf16(a0, bfrag[kc][nt], acc[0][nt], 0, 0, 0);
      acc[1][nt] = __builtin_amdgcn_mfma_f32_16x16x32_bf16(a1, bfrag[kc][nt], acc[1][nt], 0, 0, 0);
    }
  }
  float dsc0[4], dsc1[4];
#pragma unroll
  for (int r = 0; r < 4; ++r) {
    dsc0[r] = dis[r0 + lk * 4 + r];
    dsc1[r] = dis[r0 + 16 + lk * 4 + r];
  }
  unsigned short* yb = y + (size_t)r0 * C2;
#pragma unroll
  for (int nt = 0; nt < 2; ++nt)
#pragma unroll
    for (int r = 0; r < 4; ++r) {
      yb[(size_t)(lk * 4 + r) * C2 + nt * 16 + lr] = f2b(acc[0][nt][r] * dsc0[r]);
      yb[(size_t)(16 + lk * 4 + r) * C2 + nt * 16 + lr] = f2b(acc[1][nt][r] * dsc1[r]);
    }
}

// ---------------- gather2: 8 streams x 8 lanes x ushort4 (round-6 exact) -----
__global__ __launch_bounds__(256) void k_gather2(const unsigned* __restrict__ off, int n, int E,
                                                 const int* __restrict__ srcbin,
                                                 const float* __restrict__ dis,
                                                 const unsigned short* __restrict__ xw,
                                                 const float* __restrict__ b2,
                                                 float* __restrict__ out) {
  const int w = blockIdx.x * 4 + (threadIdx.x >> 6);
  if (w >= n) return;
  const int lane = threadIdx.x & 63;
  const int c4 = (lane & 7) * 4;  // column group
  const int st = lane >> 3;       // edge stream 0..7
  const float dd = dis[w];
  const unsigned beg = off[w];
  const unsigned end = (w + 1 < n) ? off[w + 1] : (unsigned)E;

  float a0 = 0.f, a1 = 0.f, a2 = 0.f, a3 = 0.f;
  float e0 = 0.f, e1 = 0.f, e2 = 0.f, e3 = 0.f;
  if (st == 0) {  // self-loop (pre-scaled)
    ushort4v u = *reinterpret_cast<const ushort4v*>(xw + (size_t)w * C2 + c4);
    a0 = b2f(u[0]); a1 = b2f(u[1]); a2 = b2f(u[2]); a3 = b2f(u[3]);
  }
  unsigned p = beg + st;
  for (; p + 8 < end; p += 16) {  // x2 unroll per stream
    int s0 = srcbin[p];
    int s1 = srcbin[p + 8];
    ushort4v u0 = *reinterpret_cast<const ushort4v*>(xw + (size_t)s0 * C2 + c4);
    ushort4v u1 = *reinterpret_cast<const ushort4v*>(xw + (size_t)s1 * C2 + c4);
    a0 += b2f(u0[0]); a1 += b2f(u0[1]); a2 += b2f(u0[2]); a3 += b2f(u0[3]);
    e0 += b2f(u1[0]); e1 += b2f(u1[1]); e2 += b2f(u1[2]); e3 += b2f(u1[3]);
  }
  if (p < end) {
    int s0 = srcbin[p];
    ushort4v u0 = *reinterpret_cast<const ushort4v*>(xw + (size_t)s0 * C2 + c4);
    a0 += b2f(u0[0]); a1 += b2f(u0[1]); a2 += b2f(u0[2]); a3 += b2f(u0[3]);
  }
  a0 += e0; a1 += e1; a2 += e2; a3 += e3;
  a0 += __shfl_xor(a0, 8, 64);  a1 += __shfl_xor(a1, 8, 64);
  a2 += __shfl_xor(a2, 8, 64);  a3 += __shfl_xor(a3, 8, 64);
  a0 += __shfl_xor(a0, 16, 64); a1 += __shfl_xor(a1, 16, 64);
  a2 += __shfl_xor(a2, 16, 64); a3 += __shfl_xor(a3, 16, 64);
  a0 += __shfl_xor(a0, 32, 64); a1 += __shfl_xor(a1, 32, 64);
  a2 += __shfl_xor(a2, 32, 64); a3 += __shfl_xor(a3, 32, 64);
  if (st == 0) {
    float4 bb = *reinterpret_cast<const float4*>(b2 + c4);
    float4 o;
    o.x = fmaf(a0, dd, bb.x);
    o.y = fmaf(a1, dd, bb.y);
    o.z = fmaf(a2, dd, bb.z);
    o.w = fmaf(a3, dd, bb.w);
    *reinterpret_cast<float4*>(out + (size_t)w * C2 + c4) = o;
  }
}

// ---------------- launch -----------------------------------------------------
extern "C" void kernel_launch(void* const* d_in, const int* in_sizes, int n_in,
                              void* d_out, int out_size, void* d_ws, size_t ws_size,
                              hipStream_t stream) {
  const float* x  = (const float*)d_in[0];
  const int*   ei = (const int*)d_in[1];
  const float* W1 = (const float*)d_in[2];
  const float* b1 = (const float*)d_in[3];
  const float* W2 = (const float*)d_in[4];
  const float* b2 = (const float*)d_in[5];
  float* out = (float*)d_out;

  const int n = in_sizes[0] / F1;   // 100000
  const int E = in_sizes[1] / 2;    // 1600000
  const int nb = (n + 255) >> BSH2; // 391 buckets (<= 512)

  char* ws = (char*)d_ws;
  size_t woff = 0;
  auto take = [&](size_t bytes) -> void* {
    void* p = ws + woff;
    woff += (bytes + 255) & ~(size_t)255;
    return p;
  };
  float*          dis    = (float*)take((size_t)n * 4);
  unsigned*       off    = (unsigned*)take((size_t)n * 4);
  unsigned*       bcnt   = (unsigned*)take((size_t)nb * 4);
  unsigned*       bo     = (unsigned*)take((size_t)nb * 4);
  unsigned*       gcnt   = (unsigned*)take((size_t)NBLK * nb * 4);
  unsigned short* wbt1   = (unsigned short*)take((size_t)H1 * F1 * 2);  // 32 KB
  unsigned short* wbt2   = (unsigned short*)take((size_t)C2 * H1 * 2);  // 4 KB
  int*            srcbin = (int*)take((size_t)E * 4);
  // big region: ebuf (E*4) aliases xw1 (n*H1*2); ebuf dead before gemm1 writes.
  char*           big    = (char*)take((size_t)E * 4 > (size_t)n * H1 * 2 ? (size_t)E * 4
                                                                           : (size_t)n * H1 * 2);
  unsigned*       ebuf = (unsigned*)big;
  unsigned short* xw1  = (unsigned short*)big;
  unsigned short* h    = (unsigned short*)take((size_t)n * H1 * 2);
  unsigned short* xw2  = (unsigned short*)take((size_t)n * C2 * 2);
  (void)ws_size;

  const int ntiles = (n + 127) / 128;
  const int chunk = (((E + NBLK - 1) / NBLK) + 255) & ~255;

  k_wconv<<<64, 256, 0, stream>>>(W1, W2, wbt1, wbt2);
  k_partA<<<NBLK, 256, 0, stream>>>(ei, E, gcnt, nb, chunk);
  k_bscan<<<nb, 128, 0, stream>>>(gcnt, bcnt, nb);
  k_scan_small<<<1, 256, 0, stream>>>(bcnt, bo, nb);
  k_partB<<<NBLK, 256, 0, stream>>>(ei, E, bo, gcnt, ebuf, nb, chunk);
  k_bucket_csr<<<nb, 256, 0, stream>>>(bo, ebuf, nb, n, E, off, dis, srcbin);

  k_gemm1<<<ntiles, 256, 0, stream>>>(x, wbt1, dis, xw1, n);
  k_gather1<<<(n + 3) / 4, 256, 0, stream>>>(off, n, E, srcbin, dis, xw1, b1, h);

  k_gemm2<<<ntiles, 256, 0, stream>>>(h, wbt2, dis, xw2, n);
  k_gather2<<<(n + 3) / 4, 256, 0, stream>>>(off, n, E, srcbin, dis, xw2, b2, out);
}